// Round 1
// 772.481 us; speedup vs baseline: 1.1703x; 1.1703x over previous
//
#include <hip/hip_runtime.h>

typedef __attribute__((ext_vector_type(8))) short s8v;
typedef __attribute__((ext_vector_type(4))) float f4v;

constexpr int BN = 16;
constexpr int TQ = 2048;
constexpr int TK = 2048;
constexpr int DH = 128;

__device__ __forceinline__ unsigned short f2bf(float f) {
  unsigned int u = __float_as_uint(f);
  u += 0x7fffu + ((u >> 16) & 1u);   // round-to-nearest-even
  return (unsigned short)(u >> 16);
}
__device__ __forceinline__ float bf2f(unsigned short h) {
  return __uint_as_float(((unsigned int)h) << 16);
}

// ---------------------------------------------------------------------------
// Kernel 1: S = Q K^T / sqrt(D) + mask*(-1e4); P = exp(S) -> attn region;
//           Z[b,k] += column sums (softmax is over the q axis!).
// 128x128 tile per block, split-bf16 3-term MFMA over 32-wide d-chunks.
// (unchanged from previous round)
// ---------------------------------------------------------------------------
__global__ __launch_bounds__(256) void qk_exp_kernel(
    const float* __restrict__ Q, const float* __restrict__ K,
    const float* __restrict__ Msk, float* __restrict__ P,
    float* __restrict__ Z)
{
  __shared__ __align__(16) unsigned short qhi[128][40];
  __shared__ __align__(16) unsigned short qlo[128][40];
  __shared__ __align__(16) unsigned short khi[128][40];
  __shared__ __align__(16) unsigned short klo[128][40];

  const int kb = blockIdx.x, qb = blockIdx.y, b = blockIdx.z;
  const int tid = threadIdx.x;
  const int wave = tid >> 6, lane = tid & 63;
  const int wr = wave >> 1, wc = wave & 1;
  const int quad = lane >> 4, l16 = lane & 15;

  f4v acc[4][4];
#pragma unroll
  for (int i = 0; i < 4; ++i)
#pragma unroll
    for (int j = 0; j < 4; ++j)
      acc[i][j] = (f4v){0.f, 0.f, 0.f, 0.f};

  const float* Qb = Q + ((size_t)b * TQ + (size_t)qb * 128) * DH;
  const float* Kb = K + ((size_t)b * TK + (size_t)kb * 128) * DH;

  for (int dc = 0; dc < DH; dc += 32) {
    __syncthreads();
#pragma unroll
    for (int i = 0; i < 4; ++i) {
      int idx = i * 256 + tid;
      int r = idx >> 3, c = (idx & 7) * 4;
      float4 qv = *(const float4*)(Qb + (size_t)r * DH + dc + c);
      float4 kv = *(const float4*)(Kb + (size_t)r * DH + dc + c);
      unsigned short h;
      h = f2bf(qv.x); qhi[r][c+0] = h; qlo[r][c+0] = f2bf(qv.x - bf2f(h));
      h = f2bf(qv.y); qhi[r][c+1] = h; qlo[r][c+1] = f2bf(qv.y - bf2f(h));
      h = f2bf(qv.z); qhi[r][c+2] = h; qlo[r][c+2] = f2bf(qv.z - bf2f(h));
      h = f2bf(qv.w); qhi[r][c+3] = h; qlo[r][c+3] = f2bf(qv.w - bf2f(h));
      h = f2bf(kv.x); khi[r][c+0] = h; klo[r][c+0] = f2bf(kv.x - bf2f(h));
      h = f2bf(kv.y); khi[r][c+1] = h; klo[r][c+1] = f2bf(kv.y - bf2f(h));
      h = f2bf(kv.z); khi[r][c+2] = h; klo[r][c+2] = f2bf(kv.z - bf2f(h));
      h = f2bf(kv.w); khi[r][c+3] = h; klo[r][c+3] = f2bf(kv.w - bf2f(h));
    }
    __syncthreads();

    s8v ah[4], al[4], bh[4], bl[4];
#pragma unroll
    for (int i = 0; i < 4; ++i) {
      ah[i] = *(const s8v*)&qhi[wr*64 + i*16 + l16][quad*8];
      al[i] = *(const s8v*)&qlo[wr*64 + i*16 + l16][quad*8];
      bh[i] = *(const s8v*)&khi[wc*64 + i*16 + l16][quad*8];
      bl[i] = *(const s8v*)&klo[wc*64 + i*16 + l16][quad*8];
    }
#pragma unroll
    for (int i = 0; i < 4; ++i)
#pragma unroll
      for (int j = 0; j < 4; ++j) {
        acc[i][j] = __builtin_amdgcn_mfma_f32_16x16x32_bf16(ah[i], bh[j], acc[i][j], 0, 0, 0);
        acc[i][j] = __builtin_amdgcn_mfma_f32_16x16x32_bf16(al[i], bh[j], acc[i][j], 0, 0, 0);
        acc[i][j] = __builtin_amdgcn_mfma_f32_16x16x32_bf16(ah[i], bl[j], acc[i][j], 0, 0, 0);
      }
  }

  const float scale = 0.08838834764831845f;  // 1/sqrt(128)
  float csum[4] = {0.f, 0.f, 0.f, 0.f};
#pragma unroll
  for (int j = 0; j < 4; ++j) {
    int col = kb * 128 + wc * 64 + j * 16 + l16;
#pragma unroll
    for (int i = 0; i < 4; ++i) {
      int row0 = qb * 128 + wr * 64 + i * 16 + quad * 4;
#pragma unroll
      for (int r = 0; r < 4; ++r) {
        size_t off = ((size_t)b * TQ + row0 + r) * TK + col;
        float s = acc[i][j][r] * scale - 10000.0f * Msk[off];
        float p = __expf(s);              // exp(-1e4) underflows to 0 (masked)
        P[off] = p;
        csum[j] += p;
      }
    }
  }
#pragma unroll
  for (int j = 0; j < 4; ++j) {
    float v = csum[j];
    v += __shfl_xor(v, 16, 64);
    v += __shfl_xor(v, 32, 64);
    if (quad == 0)
      atomicAdd(&Z[b * TK + kb * 128 + wc * 64 + j * 16 + l16], v);
  }
}

// ---------------------------------------------------------------------------
// Kernel 2a: V[b,k,d] -> Vt_hi/Vt_lo[b,d,k] (bf16 split planes) via LDS tile.
// (unchanged)
// ---------------------------------------------------------------------------
__global__ __launch_bounds__(256) void vtrans_kernel(
    const float* __restrict__ V, unsigned short* __restrict__ Vthi,
    unsigned short* __restrict__ Vtlo)
{
  __shared__ float tile[64][65];
  const int k0 = blockIdx.x * 64, d0 = blockIdx.y * 64, b = blockIdx.z;
  const int tid = threadIdx.x;
#pragma unroll
  for (int i = 0; i < 4; ++i) {
    int idx = i * 256 + tid;
    int r = idx >> 4, c = (idx & 15) * 4;
    float4 v = *(const float4*)(V + ((size_t)b * TK + k0 + r) * DH + d0 + c);
    tile[r][c] = v.x; tile[r][c+1] = v.y; tile[r][c+2] = v.z; tile[r][c+3] = v.w;
  }
  __syncthreads();
  const int dr = tid >> 2, kq = (tid & 3) * 16;
  size_t base = ((size_t)b * DH + d0 + dr) * TK + k0 + kq;
  unsigned short hbuf[16], lbuf[16];
#pragma unroll
  for (int j = 0; j < 16; ++j) {
    float f = tile[kq + j][dr];
    unsigned short h = f2bf(f);
    hbuf[j] = h;
    lbuf[j] = f2bf(f - bf2f(h));
  }
#pragma unroll
  for (int m = 0; m < 4; ++m) {
    ushort4 hv = make_ushort4(hbuf[4*m], hbuf[4*m+1], hbuf[4*m+2], hbuf[4*m+3]);
    ushort4 lv = make_ushort4(lbuf[4*m], lbuf[4*m+1], lbuf[4*m+2], lbuf[4*m+3]);
    *(ushort4*)(Vthi + base + 4*m) = hv;
    *(ushort4*)(Vtlo + base + 4*m) = lv;
  }
}

// Kernel 2b: Rz = 1/Z
__global__ __launch_bounds__(256) void rz_kernel(const float* __restrict__ Z,
                                                 float* __restrict__ Rz) {
  int i = blockIdx.x * 256 + threadIdx.x;
  Rz[i] = 1.0f / Z[i];
}

// ---------------------------------------------------------------------------
// Kernel 3: attn = P * Rz[k] (written back in place), context = attn @ V.
// NEW this round:
//   - 64q x 128d tile -> 512 blocks (2 blocks/CU instead of 1) for latency hiding
//   - double-buffered LDS + 1-ahead register prefetch (loads issued before the
//     MFMAs, ds_write after) -> one barrier per K-step
//   - 2-term split MFMA (vh*a + vl*a); dropped vh*al term (~1e-4 abs on ctx)
// Computed as context^T = V^T @ attn^T; epilogue transposes through LDS.
// ---------------------------------------------------------------------------
union __align__(16) AVSH {
  struct {
    unsigned short a[64][40];    // attn tile, bf16 (hi only)
    unsigned short vh[128][40];  // V^T hi plane
    unsigned short vl[128][40];  // V^T lo plane
  } b[2];                        // double buffer: 2 x 25600 B = 50 KB
  float ctx[64][131];            // epilogue transpose (33.5 KB, fits in union)
};

__global__ __launch_bounds__(256) void av_kernel(
    float* __restrict__ Attn, const unsigned short* __restrict__ Vthi,
    const unsigned short* __restrict__ Vtlo, const float* __restrict__ Rz,
    float* __restrict__ Ctx)
{
  __shared__ AVSH sh;
  const int qb = blockIdx.x, b = blockIdx.y;
  const int tid = threadIdx.x;
  const int wave = tid >> 6, lane = tid & 63;
  const int wr = wave >> 1, wc = wave & 1;    // wr: d-half (64), wc: q-half (32)
  const int quad = lane >> 4, l16 = lane & 15;

  f4v acc[4][2];
#pragma unroll
  for (int i = 0; i < 4; ++i)
#pragma unroll
    for (int j = 0; j < 2; ++j)
      acc[i][j] = (f4v){0.f, 0.f, 0.f, 0.f};

  float* attnB = Attn + ((size_t)b * TQ + (size_t)qb * 64) * TK;
  const unsigned short* vhB = Vthi + (size_t)b * DH * TK;
  const unsigned short* vlB = Vtlo + (size_t)b * DH * TK;
  const float* rzB = Rz + (size_t)b * TK;

  // staging coordinates (per thread, fixed)
  const int pc = (tid & 7) * 4;   // P col within 32-chunk (floats)
  const int pr = tid >> 3;        // P row 0..31 (u=0); +32 for u=1
  const int vc = (tid & 3) * 8;   // V col within 32-chunk (shorts)
  const int vr = tid >> 2;        // V row 0..63 (u=0); +64 for u=1

  float4 pv0, pv1, rzv;
  uint4 vh0, vh1, vl0, vl1;

  auto load_chunk = [&](int kc) {
    pv0 = *(const float4*)(attnB + (size_t)pr * TK + kc + pc);
    pv1 = *(const float4*)(attnB + (size_t)(pr + 32) * TK + kc + pc);
    rzv = *(const float4*)(rzB + kc + pc);
    vh0 = *(const uint4*)(vhB + (size_t)vr * TK + kc + vc);
    vh1 = *(const uint4*)(vhB + (size_t)(vr + 64) * TK + kc + vc);
    vl0 = *(const uint4*)(vlB + (size_t)vr * TK + kc + vc);
    vl1 = *(const uint4*)(vlB + (size_t)(vr + 64) * TK + kc + vc);
  };

  auto stage_chunk = [&](int kc, int B) {
    float4 a0, a1;
    a0.x = pv0.x * rzv.x; a0.y = pv0.y * rzv.y;
    a0.z = pv0.z * rzv.z; a0.w = pv0.w * rzv.w;
    a1.x = pv1.x * rzv.x; a1.y = pv1.y * rzv.y;
    a1.z = pv1.z * rzv.z; a1.w = pv1.w * rzv.w;
    // final normalized attn output (in place)
    *(float4*)(attnB + (size_t)pr * TK + kc + pc) = a0;
    *(float4*)(attnB + (size_t)(pr + 32) * TK + kc + pc) = a1;
    *(ushort4*)&sh.b[B].a[pr][pc] =
        make_ushort4(f2bf(a0.x), f2bf(a0.y), f2bf(a0.z), f2bf(a0.w));
    *(ushort4*)&sh.b[B].a[pr + 32][pc] =
        make_ushort4(f2bf(a1.x), f2bf(a1.y), f2bf(a1.z), f2bf(a1.w));
    *(uint4*)&sh.b[B].vh[vr][vc] = vh0;
    *(uint4*)&sh.b[B].vh[vr + 64][vc] = vh1;
    *(uint4*)&sh.b[B].vl[vr][vc] = vl0;
    *(uint4*)&sh.b[B].vl[vr + 64][vc] = vl1;
  };

  load_chunk(0);
  stage_chunk(0, 0);
  __syncthreads();

  int cur = 0;
  constexpr int NT = TK / 32;
  for (int t = 0; t < NT; ++t) {
    if (t + 1 < NT) load_chunk((t + 1) * 32);   // issue early; waited at stage

    s8v vhf[4], vlf[4], pf[2];
#pragma unroll
    for (int i = 0; i < 4; ++i) {
      vhf[i] = *(const s8v*)&sh.b[cur].vh[wr * 64 + i * 16 + l16][quad * 8];
      vlf[i] = *(const s8v*)&sh.b[cur].vl[wr * 64 + i * 16 + l16][quad * 8];
    }
#pragma unroll
    for (int j = 0; j < 2; ++j)
      pf[j] = *(const s8v*)&sh.b[cur].a[wc * 32 + j * 16 + l16][quad * 8];

#pragma unroll
    for (int i = 0; i < 4; ++i)
#pragma unroll
      for (int j = 0; j < 2; ++j) {
        acc[i][j] = __builtin_amdgcn_mfma_f32_16x16x32_bf16(vhf[i], pf[j], acc[i][j], 0, 0, 0);
        acc[i][j] = __builtin_amdgcn_mfma_f32_16x16x32_bf16(vlf[i], pf[j], acc[i][j], 0, 0, 0);
      }

    if (t + 1 < NT) {
      stage_chunk((t + 1) * 32, cur ^ 1);  // buf[cur^1] free since last barrier
      __syncthreads();
      cur ^= 1;
    }
  }

  // Epilogue: acc holds context^T (m=d, n=q). Single-pass transpose via LDS
  // (all 4 waves own disjoint (q,d) regions), then coalesced float4 stores.
  __syncthreads();
#pragma unroll
  for (int i = 0; i < 4; ++i)
#pragma unroll
    for (int j = 0; j < 2; ++j)
#pragma unroll
      for (int r = 0; r < 4; ++r)
        sh.ctx[wc * 32 + j * 16 + l16][wr * 64 + i * 16 + quad * 4 + r] = acc[i][j][r];
  __syncthreads();
#pragma unroll
  for (int it = 0; it < 8; ++it) {
    int idx = it * 256 + tid;
    int r = idx >> 5, c = (idx & 31) * 4;
    float4 v;
    v.x = sh.ctx[r][c];     v.y = sh.ctx[r][c + 1];
    v.z = sh.ctx[r][c + 2]; v.w = sh.ctx[r][c + 3];
    *(float4*)(Ctx + ((size_t)b * TQ + qb * 64 + r) * DH + c) = v;
  }
}

// ---------------------------------------------------------------------------
extern "C" void kernel_launch(void* const* d_in, const int* in_sizes, int n_in,
                              void* d_out, int out_size, void* d_ws, size_t ws_size,
                              hipStream_t stream)
{
  const float* Q = (const float*)d_in[0];
  const float* K = (const float*)d_in[1];
  const float* V = (const float*)d_in[2];
  const float* M = (const float*)d_in[3];

  float* ctx  = (float*)d_out;
  float* attn = ctx + (size_t)BN * TQ * DH;   // outputs: context ++ attn

  // workspace layout: Z (128 KB) | @1MB: Vt_hi (8MB) | Vt_lo (8MB) | Rz (128KB)
  char* ws = (char*)d_ws;
  float* Z = (float*)ws;
  unsigned short* Vthi = (unsigned short*)(ws + (1 << 20));
  unsigned short* Vtlo = Vthi + (size_t)BN * DH * TK;
  float* Rz = (float*)(ws + (1 << 20) + (size_t)BN * DH * TK * 4);

  hipMemsetAsync(Z, 0, (size_t)BN * TK * sizeof(float), stream);
  vtrans_kernel<<<dim3(TK/64, DH/64, BN), 256, 0, stream>>>(V, Vthi, Vtlo);
  qk_exp_kernel<<<dim3(TK/128, TQ/128, BN), 256, 0, stream>>>(Q, K, M, attn, Z);
  rz_kernel<<<dim3((BN*TK)/256), 256, 0, stream>>>(Z, Rz);
  av_kernel<<<dim3(TQ/64, BN), 256, 0, stream>>>(attn, Vthi, Vtlo, Rz, ctx);
}

// Round 2
// 742.020 us; speedup vs baseline: 1.2183x; 1.0411x over previous
//
#include <hip/hip_runtime.h>

typedef __attribute__((ext_vector_type(8))) short s8v;
typedef __attribute__((ext_vector_type(4))) float f4v;

constexpr int BN = 16;
constexpr int TQ = 2048;
constexpr int TK = 2048;
constexpr int DH = 128;

__device__ __forceinline__ unsigned short f2bf(float f) {
  unsigned int u = __float_as_uint(f);
  u += 0x7fffu + ((u >> 16) & 1u);   // round-to-nearest-even
  return (unsigned short)(u >> 16);
}
__device__ __forceinline__ float bf2f(unsigned short h) {
  return __uint_as_float(((unsigned int)h) << 16);
}

// ---------------------------------------------------------------------------
// Kernel 0: compress binary f32 mask (0.0/1.0) -> 1 bit per element.
// Perfectly coalesced: each block reads 1024 consecutive floats (4KB),
// assembles 32 uint32 words via LDS nibble exchange, stores 128B.
// ---------------------------------------------------------------------------
__global__ __launch_bounds__(256) void maskbits_kernel(
    const float* __restrict__ Msk, unsigned int* __restrict__ Mb)
{
  __shared__ unsigned char nib[256];
  const int tid = threadIdx.x;
  const size_t base = (size_t)blockIdx.x * 1024;
  float4 v = *(const float4*)(Msk + base + (size_t)tid * 4);
  unsigned char n = (v.x != 0.f ? 1u : 0u) | (v.y != 0.f ? 2u : 0u) |
                    (v.z != 0.f ? 4u : 0u) | (v.w != 0.f ? 8u : 0u);
  nib[tid] = n;
  __syncthreads();
  if (tid < 32) {
    unsigned int w = 0;
#pragma unroll
    for (int j = 0; j < 8; ++j)
      w |= (unsigned int)nib[tid * 8 + j] << (j * 4);
    Mb[(size_t)blockIdx.x * 32 + tid] = w;
  }
}

// ---------------------------------------------------------------------------
// Kernel 1: S = Q K^T / sqrt(D); P = (masked ? 0 : exp(S)) -> attn region;
//           Z[b,k] += column sums (softmax is over the q axis!).
// 128x128 tile, split-bf16 3-term MFMA.
// NEW: bitmask epilogue (L2-resident 8B broadcast loads instead of 268MB
//      scattered f32); B-fragments loaded inside j-loop + launch_bounds(256,4)
//      to get VGPR <= 128 -> 4 blocks/CU instead of 2.
// ---------------------------------------------------------------------------
__global__ __launch_bounds__(256, 4) void qk_exp_kernel(
    const float* __restrict__ Q, const float* __restrict__ K,
    const unsigned int* __restrict__ Mb, float* __restrict__ P,
    float* __restrict__ Z)
{
  __shared__ __align__(16) unsigned short qhi[128][40];
  __shared__ __align__(16) unsigned short qlo[128][40];
  __shared__ __align__(16) unsigned short khi[128][40];
  __shared__ __align__(16) unsigned short klo[128][40];

  const int kb = blockIdx.x, qb = blockIdx.y, b = blockIdx.z;
  const int tid = threadIdx.x;
  const int wave = tid >> 6, lane = tid & 63;
  const int wr = wave >> 1, wc = wave & 1;
  const int quad = lane >> 4, l16 = lane & 15;

  f4v acc[4][4];
#pragma unroll
  for (int i = 0; i < 4; ++i)
#pragma unroll
    for (int j = 0; j < 4; ++j)
      acc[i][j] = (f4v){0.f, 0.f, 0.f, 0.f};

  const float* Qb = Q + ((size_t)b * TQ + (size_t)qb * 128) * DH;
  const float* Kb = K + ((size_t)b * TK + (size_t)kb * 128) * DH;

  for (int dc = 0; dc < DH; dc += 32) {
    __syncthreads();
#pragma unroll
    for (int i = 0; i < 4; ++i) {
      int idx = i * 256 + tid;
      int r = idx >> 3, c = (idx & 7) * 4;
      float4 qv = *(const float4*)(Qb + (size_t)r * DH + dc + c);
      float4 kv = *(const float4*)(Kb + (size_t)r * DH + dc + c);
      unsigned short h;
      h = f2bf(qv.x); qhi[r][c+0] = h; qlo[r][c+0] = f2bf(qv.x - bf2f(h));
      h = f2bf(qv.y); qhi[r][c+1] = h; qlo[r][c+1] = f2bf(qv.y - bf2f(h));
      h = f2bf(qv.z); qhi[r][c+2] = h; qlo[r][c+2] = f2bf(qv.z - bf2f(h));
      h = f2bf(qv.w); qhi[r][c+3] = h; qlo[r][c+3] = f2bf(qv.w - bf2f(h));
      h = f2bf(kv.x); khi[r][c+0] = h; klo[r][c+0] = f2bf(kv.x - bf2f(h));
      h = f2bf(kv.y); khi[r][c+1] = h; klo[r][c+1] = f2bf(kv.y - bf2f(h));
      h = f2bf(kv.z); khi[r][c+2] = h; klo[r][c+2] = f2bf(kv.z - bf2f(h));
      h = f2bf(kv.w); khi[r][c+3] = h; klo[r][c+3] = f2bf(kv.w - bf2f(h));
    }
    __syncthreads();

    s8v ah[4], al[4];
#pragma unroll
    for (int i = 0; i < 4; ++i) {
      ah[i] = *(const s8v*)&qhi[wr*64 + i*16 + l16][quad*8];
      al[i] = *(const s8v*)&qlo[wr*64 + i*16 + l16][quad*8];
    }
#pragma unroll
    for (int j = 0; j < 4; ++j) {
      s8v bh = *(const s8v*)&khi[wc*64 + j*16 + l16][quad*8];
      s8v bl = *(const s8v*)&klo[wc*64 + j*16 + l16][quad*8];
#pragma unroll
      for (int i = 0; i < 4; ++i) {
        acc[i][j] = __builtin_amdgcn_mfma_f32_16x16x32_bf16(ah[i], bh, acc[i][j], 0, 0, 0);
        acc[i][j] = __builtin_amdgcn_mfma_f32_16x16x32_bf16(al[i], bh, acc[i][j], 0, 0, 0);
        acc[i][j] = __builtin_amdgcn_mfma_f32_16x16x32_bf16(ah[i], bl, acc[i][j], 0, 0, 0);
      }
    }
  }

  const float scale = 0.08838834764831845f;  // 1/sqrt(128)
  const unsigned int* MbB = Mb + (size_t)b * TQ * (TK / 32) + kb * 4 + wc * 2;
  float csum[4] = {0.f, 0.f, 0.f, 0.f};
#pragma unroll
  for (int i = 0; i < 4; ++i) {
    int row0 = qb * 128 + wr * 64 + i * 16 + quad * 4;
    uint2 w[4];
#pragma unroll
    for (int r = 0; r < 4; ++r)
      w[r] = *(const uint2*)(MbB + (size_t)(row0 + r) * (TK / 32));
#pragma unroll
    for (int r = 0; r < 4; ++r) {
      size_t rowoff = ((size_t)b * TQ + row0 + r) * TK + kb * 128 + wc * 64;
#pragma unroll
      for (int j = 0; j < 4; ++j) {
        unsigned int bits = (j < 2) ? w[r].x : w[r].y;
        unsigned int m = (bits >> ((j & 1) * 16 + l16)) & 1u;
        float p = m ? 0.f : __expf(acc[i][j][r] * scale);
        P[rowoff + j * 16 + l16] = p;
        csum[j] += p;
      }
    }
  }
#pragma unroll
  for (int j = 0; j < 4; ++j) {
    float v = csum[j];
    v += __shfl_xor(v, 16, 64);
    v += __shfl_xor(v, 32, 64);
    if (quad == 0)
      atomicAdd(&Z[b * TK + kb * 128 + wc * 64 + j * 16 + l16], v);
  }
}

// ---------------------------------------------------------------------------
// Kernel 2a: V[b,k,d] -> Vt_hi/Vt_lo[b,d,k] (bf16 split planes) via LDS tile.
// (unchanged)
// ---------------------------------------------------------------------------
__global__ __launch_bounds__(256) void vtrans_kernel(
    const float* __restrict__ V, unsigned short* __restrict__ Vthi,
    unsigned short* __restrict__ Vtlo)
{
  __shared__ float tile[64][65];
  const int k0 = blockIdx.x * 64, d0 = blockIdx.y * 64, b = blockIdx.z;
  const int tid = threadIdx.x;
#pragma unroll
  for (int i = 0; i < 4; ++i) {
    int idx = i * 256 + tid;
    int r = idx >> 4, c = (idx & 15) * 4;
    float4 v = *(const float4*)(V + ((size_t)b * TK + k0 + r) * DH + d0 + c);
    tile[r][c] = v.x; tile[r][c+1] = v.y; tile[r][c+2] = v.z; tile[r][c+3] = v.w;
  }
  __syncthreads();
  const int dr = tid >> 2, kq = (tid & 3) * 16;
  size_t base = ((size_t)b * DH + d0 + dr) * TK + k0 + kq;
  unsigned short hbuf[16], lbuf[16];
#pragma unroll
  for (int j = 0; j < 16; ++j) {
    float f = tile[kq + j][dr];
    unsigned short h = f2bf(f);
    hbuf[j] = h;
    lbuf[j] = f2bf(f - bf2f(h));
  }
#pragma unroll
  for (int m = 0; m < 4; ++m) {
    ushort4 hv = make_ushort4(hbuf[4*m], hbuf[4*m+1], hbuf[4*m+2], hbuf[4*m+3]);
    ushort4 lv = make_ushort4(lbuf[4*m], lbuf[4*m+1], lbuf[4*m+2], lbuf[4*m+3]);
    *(ushort4*)(Vthi + base + 4*m) = hv;
    *(ushort4*)(Vtlo + base + 4*m) = lv;
  }
}

// Kernel 2b: Rz = 1/Z
__global__ __launch_bounds__(256) void rz_kernel(const float* __restrict__ Z,
                                                 float* __restrict__ Rz) {
  int i = blockIdx.x * 256 + threadIdx.x;
  Rz[i] = 1.0f / Z[i];
}

// ---------------------------------------------------------------------------
// Kernel 3: attn = P * Rz[k] (written back in place), context = attn @ V.
// (unchanged from round 1: 64q x 128d tile, double-buffered, 2-term split)
// ---------------------------------------------------------------------------
union __align__(16) AVSH {
  struct {
    unsigned short a[64][40];    // attn tile, bf16 (hi only)
    unsigned short vh[128][40];  // V^T hi plane
    unsigned short vl[128][40];  // V^T lo plane
  } b[2];                        // double buffer: 2 x 25600 B = 50 KB
  float ctx[64][131];            // epilogue transpose
};

__global__ __launch_bounds__(256) void av_kernel(
    float* __restrict__ Attn, const unsigned short* __restrict__ Vthi,
    const unsigned short* __restrict__ Vtlo, const float* __restrict__ Rz,
    float* __restrict__ Ctx)
{
  __shared__ AVSH sh;
  const int qb = blockIdx.x, b = blockIdx.y;
  const int tid = threadIdx.x;
  const int wave = tid >> 6, lane = tid & 63;
  const int wr = wave >> 1, wc = wave & 1;
  const int quad = lane >> 4, l16 = lane & 15;

  f4v acc[4][2];
#pragma unroll
  for (int i = 0; i < 4; ++i)
#pragma unroll
    for (int j = 0; j < 2; ++j)
      acc[i][j] = (f4v){0.f, 0.f, 0.f, 0.f};

  float* attnB = Attn + ((size_t)b * TQ + (size_t)qb * 64) * TK;
  const unsigned short* vhB = Vthi + (size_t)b * DH * TK;
  const unsigned short* vlB = Vtlo + (size_t)b * DH * TK;
  const float* rzB = Rz + (size_t)b * TK;

  const int pc = (tid & 7) * 4;
  const int pr = tid >> 3;
  const int vc = (tid & 3) * 8;
  const int vr = tid >> 2;

  float4 pv0, pv1, rzv;
  uint4 vh0, vh1, vl0, vl1;

  auto load_chunk = [&](int kc) {
    pv0 = *(const float4*)(attnB + (size_t)pr * TK + kc + pc);
    pv1 = *(const float4*)(attnB + (size_t)(pr + 32) * TK + kc + pc);
    rzv = *(const float4*)(rzB + kc + pc);
    vh0 = *(const uint4*)(vhB + (size_t)vr * TK + kc + vc);
    vh1 = *(const uint4*)(vhB + (size_t)(vr + 64) * TK + kc + vc);
    vl0 = *(const uint4*)(vlB + (size_t)vr * TK + kc + vc);
    vl1 = *(const uint4*)(vlB + (size_t)(vr + 64) * TK + kc + vc);
  };

  auto stage_chunk = [&](int kc, int B) {
    float4 a0, a1;
    a0.x = pv0.x * rzv.x; a0.y = pv0.y * rzv.y;
    a0.z = pv0.z * rzv.z; a0.w = pv0.w * rzv.w;
    a1.x = pv1.x * rzv.x; a1.y = pv1.y * rzv.y;
    a1.z = pv1.z * rzv.z; a1.w = pv1.w * rzv.w;
    *(float4*)(attnB + (size_t)pr * TK + kc + pc) = a0;
    *(float4*)(attnB + (size_t)(pr + 32) * TK + kc + pc) = a1;
    *(ushort4*)&sh.b[B].a[pr][pc] =
        make_ushort4(f2bf(a0.x), f2bf(a0.y), f2bf(a0.z), f2bf(a0.w));
    *(ushort4*)&sh.b[B].a[pr + 32][pc] =
        make_ushort4(f2bf(a1.x), f2bf(a1.y), f2bf(a1.z), f2bf(a1.w));
    *(uint4*)&sh.b[B].vh[vr][vc] = vh0;
    *(uint4*)&sh.b[B].vh[vr + 64][vc] = vh1;
    *(uint4*)&sh.b[B].vl[vr][vc] = vl0;
    *(uint4*)&sh.b[B].vl[vr + 64][vc] = vl1;
  };

  load_chunk(0);
  stage_chunk(0, 0);
  __syncthreads();

  int cur = 0;
  constexpr int NT = TK / 32;
  for (int t = 0; t < NT; ++t) {
    if (t + 1 < NT) load_chunk((t + 1) * 32);

    s8v vhf[4], vlf[4], pf[2];
#pragma unroll
    for (int i = 0; i < 4; ++i) {
      vhf[i] = *(const s8v*)&sh.b[cur].vh[wr * 64 + i * 16 + l16][quad * 8];
      vlf[i] = *(const s8v*)&sh.b[cur].vl[wr * 64 + i * 16 + l16][quad * 8];
    }
#pragma unroll
    for (int j = 0; j < 2; ++j)
      pf[j] = *(const s8v*)&sh.b[cur].a[wc * 32 + j * 16 + l16][quad * 8];

#pragma unroll
    for (int i = 0; i < 4; ++i)
#pragma unroll
      for (int j = 0; j < 2; ++j) {
        acc[i][j] = __builtin_amdgcn_mfma_f32_16x16x32_bf16(vhf[i], pf[j], acc[i][j], 0, 0, 0);
        acc[i][j] = __builtin_amdgcn_mfma_f32_16x16x32_bf16(vlf[i], pf[j], acc[i][j], 0, 0, 0);
      }

    if (t + 1 < NT) {
      stage_chunk((t + 1) * 32, cur ^ 1);
      __syncthreads();
      cur ^= 1;
    }
  }

  __syncthreads();
#pragma unroll
  for (int i = 0; i < 4; ++i)
#pragma unroll
    for (int j = 0; j < 2; ++j)
#pragma unroll
      for (int r = 0; r < 4; ++r)
        sh.ctx[wc * 32 + j * 16 + l16][wr * 64 + i * 16 + quad * 4 + r] = acc[i][j][r];
  __syncthreads();
#pragma unroll
  for (int it = 0; it < 8; ++it) {
    int idx = it * 256 + tid;
    int r = idx >> 5, c = (idx & 31) * 4;
    float4 v;
    v.x = sh.ctx[r][c];     v.y = sh.ctx[r][c + 1];
    v.z = sh.ctx[r][c + 2]; v.w = sh.ctx[r][c + 3];
    *(float4*)(Ctx + ((size_t)b * TQ + qb * 64 + r) * DH + c) = v;
  }
}

// ---------------------------------------------------------------------------
extern "C" void kernel_launch(void* const* d_in, const int* in_sizes, int n_in,
                              void* d_out, int out_size, void* d_ws, size_t ws_size,
                              hipStream_t stream)
{
  const float* Q = (const float*)d_in[0];
  const float* K = (const float*)d_in[1];
  const float* V = (const float*)d_in[2];
  const float* M = (const float*)d_in[3];

  float* ctx  = (float*)d_out;
  float* attn = ctx + (size_t)BN * TQ * DH;   // outputs: context ++ attn

  // workspace layout:
  //   Z  @ 0       (128 KB)
  //   Rz @ 128KB   (128 KB)
  //   Vthi @ 1MB   (8 MB)
  //   Vtlo @ 9MB   (8 MB)
  //   Mb  @ 17MB   (8 MB bitmask)
  char* ws = (char*)d_ws;
  float* Z  = (float*)ws;
  float* Rz = (float*)(ws + (128 << 10));
  unsigned short* Vthi = (unsigned short*)(ws + (1 << 20));
  unsigned short* Vtlo = Vthi + (size_t)BN * DH * TK;
  unsigned int* Mbits = (unsigned int*)(ws + (17u << 20));

  hipMemsetAsync(Z, 0, (size_t)BN * TK * sizeof(float), stream);
  maskbits_kernel<<<dim3((BN * TQ * TK) / 1024), 256, 0, stream>>>(M, Mbits);
  vtrans_kernel<<<dim3(TK/64, DH/64, BN), 256, 0, stream>>>(V, Vthi, Vtlo);
  qk_exp_kernel<<<dim3(TK/128, TQ/128, BN), 256, 0, stream>>>(Q, K, Mbits, attn, Z);
  rz_kernel<<<dim3((BN*TK)/256), 256, 0, stream>>>(Z, Rz);
  av_kernel<<<dim3(TQ/64, BN), 256, 0, stream>>>(attn, Vthi, Vtlo, Rz, ctx);
}

// Round 3
// 710.264 us; speedup vs baseline: 1.2728x; 1.0447x over previous
//
#include <hip/hip_runtime.h>

typedef __attribute__((ext_vector_type(8))) short s8v;
typedef __attribute__((ext_vector_type(4))) float f4v;

constexpr int BN = 16;
constexpr int TQ = 2048;
constexpr int TK = 2048;
constexpr int DH = 128;

__device__ __forceinline__ unsigned short f2bf(float f) {
  unsigned int u = __float_as_uint(f);
  u += 0x7fffu + ((u >> 16) & 1u);   // round-to-nearest-even
  return (unsigned short)(u >> 16);
}
__device__ __forceinline__ float bf2f(unsigned short h) {
  return __uint_as_float(((unsigned int)h) << 16);
}

// ---------------------------------------------------------------------------
// Kernel 1: S = Q K^T / sqrt(D); P = (masked ? 0 : exp(S)) -> attn region;
//           Z[b,k] += column sums (softmax is over the q axis!).
// 128x128 tile, split-bf16 3-term MFMA.
// NEW this round: mask is read directly by this kernel (the standalone
// maskbits pass is gone). After the MFMA loop the Q/K LDS tiles are dead;
// the block's 128x128 f32 mask tile is restaged there as ushort 0/1
// ([128][132] stride -> conflict-free epilogue reads). Each mask element
// belongs to exactly one block, so no duplicated traffic; the read overlaps
// resident blocks' MFMA work instead of costing a dedicated 55us kernel.
// ---------------------------------------------------------------------------
union QKSH {
  struct {
    unsigned short qhi[128][40];
    unsigned short qlo[128][40];
    unsigned short khi[128][40];
    unsigned short klo[128][40];
  } s;                                  // 40960 B (MFMA phase)
  unsigned short msk[128][132];         // 33792 B (epilogue phase)
};

__global__ __launch_bounds__(256, 4) void qk_exp_kernel(
    const float* __restrict__ Q, const float* __restrict__ K,
    const float* __restrict__ Msk, float* __restrict__ P,
    float* __restrict__ Z)
{
  __shared__ QKSH sh;

  const int kb = blockIdx.x, qb = blockIdx.y, b = blockIdx.z;
  const int tid = threadIdx.x;
  const int wave = tid >> 6, lane = tid & 63;
  const int wr = wave >> 1, wc = wave & 1;
  const int quad = lane >> 4, l16 = lane & 15;

  f4v acc[4][4];
#pragma unroll
  for (int i = 0; i < 4; ++i)
#pragma unroll
    for (int j = 0; j < 4; ++j)
      acc[i][j] = (f4v){0.f, 0.f, 0.f, 0.f};

  const float* Qb = Q + ((size_t)b * TQ + (size_t)qb * 128) * DH;
  const float* Kb = K + ((size_t)b * TK + (size_t)kb * 128) * DH;

  for (int dc = 0; dc < DH; dc += 32) {
    __syncthreads();
#pragma unroll
    for (int i = 0; i < 4; ++i) {
      int idx = i * 256 + tid;
      int r = idx >> 3, c = (idx & 7) * 4;
      float4 qv = *(const float4*)(Qb + (size_t)r * DH + dc + c);
      float4 kv = *(const float4*)(Kb + (size_t)r * DH + dc + c);
      unsigned short h;
      h = f2bf(qv.x); sh.s.qhi[r][c+0] = h; sh.s.qlo[r][c+0] = f2bf(qv.x - bf2f(h));
      h = f2bf(qv.y); sh.s.qhi[r][c+1] = h; sh.s.qlo[r][c+1] = f2bf(qv.y - bf2f(h));
      h = f2bf(qv.z); sh.s.qhi[r][c+2] = h; sh.s.qlo[r][c+2] = f2bf(qv.z - bf2f(h));
      h = f2bf(qv.w); sh.s.qhi[r][c+3] = h; sh.s.qlo[r][c+3] = f2bf(qv.w - bf2f(h));
      h = f2bf(kv.x); sh.s.khi[r][c+0] = h; sh.s.klo[r][c+0] = f2bf(kv.x - bf2f(h));
      h = f2bf(kv.y); sh.s.khi[r][c+1] = h; sh.s.klo[r][c+1] = f2bf(kv.y - bf2f(h));
      h = f2bf(kv.z); sh.s.khi[r][c+2] = h; sh.s.klo[r][c+2] = f2bf(kv.z - bf2f(h));
      h = f2bf(kv.w); sh.s.khi[r][c+3] = h; sh.s.klo[r][c+3] = f2bf(kv.w - bf2f(h));
    }
    __syncthreads();

    s8v ah[4], al[4];
#pragma unroll
    for (int i = 0; i < 4; ++i) {
      ah[i] = *(const s8v*)&sh.s.qhi[wr*64 + i*16 + l16][quad*8];
      al[i] = *(const s8v*)&sh.s.qlo[wr*64 + i*16 + l16][quad*8];
    }
#pragma unroll
    for (int j = 0; j < 4; ++j) {
      s8v bh = *(const s8v*)&sh.s.khi[wc*64 + j*16 + l16][quad*8];
      s8v bl = *(const s8v*)&sh.s.klo[wc*64 + j*16 + l16][quad*8];
#pragma unroll
      for (int i = 0; i < 4; ++i) {
        acc[i][j] = __builtin_amdgcn_mfma_f32_16x16x32_bf16(ah[i], bh, acc[i][j], 0, 0, 0);
        acc[i][j] = __builtin_amdgcn_mfma_f32_16x16x32_bf16(al[i], bh, acc[i][j], 0, 0, 0);
        acc[i][j] = __builtin_amdgcn_mfma_f32_16x16x32_bf16(ah[i], bl, acc[i][j], 0, 0, 0);
      }
    }
  }

  // ---- mask restage: Q/K tiles are dead; all waves' ds_reads done -> barrier
  __syncthreads();
  {
    const float* MB = Msk + ((size_t)b * TQ + (size_t)qb * 128) * TK + (size_t)kb * 128;
#pragma unroll
    for (int it = 0; it < 16; ++it) {
      int idx = it * 256 + tid;
      int r = idx >> 5, c = (idx & 31) * 4;
      float4 mv = *(const float4*)(MB + (size_t)r * TK + c);
      ushort4 mu;
      mu.x = (mv.x != 0.f); mu.y = (mv.y != 0.f);
      mu.z = (mv.z != 0.f); mu.w = (mv.w != 0.f);
      *(ushort4*)&sh.msk[r][c] = mu;
    }
  }
  __syncthreads();

  const float scale = 0.08838834764831845f;  // 1/sqrt(128)
  float csum[4] = {0.f, 0.f, 0.f, 0.f};
#pragma unroll
  for (int i = 0; i < 4; ++i) {
    int lr0 = wr * 64 + i * 16 + quad * 4;     // local row within tile
#pragma unroll
    for (int r = 0; r < 4; ++r) {
      size_t rowoff = ((size_t)b * TQ + qb * 128 + lr0 + r) * TK + kb * 128 + wc * 64;
      const unsigned short* mrow = &sh.msk[lr0 + r][wc * 64];
#pragma unroll
      for (int j = 0; j < 4; ++j) {
        unsigned short m = mrow[j * 16 + l16];
        float p = m ? 0.f : __expf(acc[i][j][r] * scale);
        P[rowoff + j * 16 + l16] = p;
        csum[j] += p;
      }
    }
  }
#pragma unroll
  for (int j = 0; j < 4; ++j) {
    float v = csum[j];
    v += __shfl_xor(v, 16, 64);
    v += __shfl_xor(v, 32, 64);
    if (quad == 0)
      atomicAdd(&Z[b * TK + kb * 128 + wc * 64 + j * 16 + l16], v);
  }
}

// ---------------------------------------------------------------------------
// Kernel 2a: V[b,k,d] -> Vt_hi/Vt_lo[b,d,k] (bf16 split planes) via LDS tile.
// (unchanged)
// ---------------------------------------------------------------------------
__global__ __launch_bounds__(256) void vtrans_kernel(
    const float* __restrict__ V, unsigned short* __restrict__ Vthi,
    unsigned short* __restrict__ Vtlo)
{
  __shared__ float tile[64][65];
  const int k0 = blockIdx.x * 64, d0 = blockIdx.y * 64, b = blockIdx.z;
  const int tid = threadIdx.x;
#pragma unroll
  for (int i = 0; i < 4; ++i) {
    int idx = i * 256 + tid;
    int r = idx >> 4, c = (idx & 15) * 4;
    float4 v = *(const float4*)(V + ((size_t)b * TK + k0 + r) * DH + d0 + c);
    tile[r][c] = v.x; tile[r][c+1] = v.y; tile[r][c+2] = v.z; tile[r][c+3] = v.w;
  }
  __syncthreads();
  const int dr = tid >> 2, kq = (tid & 3) * 16;
  size_t base = ((size_t)b * DH + d0 + dr) * TK + k0 + kq;
  unsigned short hbuf[16], lbuf[16];
#pragma unroll
  for (int j = 0; j < 16; ++j) {
    float f = tile[kq + j][dr];
    unsigned short h = f2bf(f);
    hbuf[j] = h;
    lbuf[j] = f2bf(f - bf2f(h));
  }
#pragma unroll
  for (int m = 0; m < 4; ++m) {
    ushort4 hv = make_ushort4(hbuf[4*m], hbuf[4*m+1], hbuf[4*m+2], hbuf[4*m+3]);
    ushort4 lv = make_ushort4(lbuf[4*m], lbuf[4*m+1], lbuf[4*m+2], lbuf[4*m+3]);
    *(ushort4*)(Vthi + base + 4*m) = hv;
    *(ushort4*)(Vtlo + base + 4*m) = lv;
  }
}

// Kernel 2b: Rz = 1/Z
__global__ __launch_bounds__(256) void rz_kernel(const float* __restrict__ Z,
                                                 float* __restrict__ Rz) {
  int i = blockIdx.x * 256 + threadIdx.x;
  Rz[i] = 1.0f / Z[i];
}

// ---------------------------------------------------------------------------
// Kernel 3: attn = P * Rz[k] (written back in place), context = attn @ V.
// (unchanged: 64q x 128d tile, double-buffered, 2-term split)
// ---------------------------------------------------------------------------
union __align__(16) AVSH {
  struct {
    unsigned short a[64][40];    // attn tile, bf16 (hi only)
    unsigned short vh[128][40];  // V^T hi plane
    unsigned short vl[128][40];  // V^T lo plane
  } b[2];                        // double buffer: 2 x 25600 B = 50 KB
  float ctx[64][131];            // epilogue transpose
};

__global__ __launch_bounds__(256) void av_kernel(
    float* __restrict__ Attn, const unsigned short* __restrict__ Vthi,
    const unsigned short* __restrict__ Vtlo, const float* __restrict__ Rz,
    float* __restrict__ Ctx)
{
  __shared__ AVSH sh;
  const int qb = blockIdx.x, b = blockIdx.y;
  const int tid = threadIdx.x;
  const int wave = tid >> 6, lane = tid & 63;
  const int wr = wave >> 1, wc = wave & 1;
  const int quad = lane >> 4, l16 = lane & 15;

  f4v acc[4][2];
#pragma unroll
  for (int i = 0; i < 4; ++i)
#pragma unroll
    for (int j = 0; j < 2; ++j)
      acc[i][j] = (f4v){0.f, 0.f, 0.f, 0.f};

  float* attnB = Attn + ((size_t)b * TQ + (size_t)qb * 64) * TK;
  const unsigned short* vhB = Vthi + (size_t)b * DH * TK;
  const unsigned short* vlB = Vtlo + (size_t)b * DH * TK;
  const float* rzB = Rz + (size_t)b * TK;

  const int pc = (tid & 7) * 4;
  const int pr = tid >> 3;
  const int vc = (tid & 3) * 8;
  const int vr = tid >> 2;

  float4 pv0, pv1, rzv;
  uint4 vh0, vh1, vl0, vl1;

  auto load_chunk = [&](int kc) {
    pv0 = *(const float4*)(attnB + (size_t)pr * TK + kc + pc);
    pv1 = *(const float4*)(attnB + (size_t)(pr + 32) * TK + kc + pc);
    rzv = *(const float4*)(rzB + kc + pc);
    vh0 = *(const uint4*)(vhB + (size_t)vr * TK + kc + vc);
    vh1 = *(const uint4*)(vhB + (size_t)(vr + 64) * TK + kc + vc);
    vl0 = *(const uint4*)(vlB + (size_t)vr * TK + kc + vc);
    vl1 = *(const uint4*)(vlB + (size_t)(vr + 64) * TK + kc + vc);
  };

  auto stage_chunk = [&](int kc, int B) {
    float4 a0, a1;
    a0.x = pv0.x * rzv.x; a0.y = pv0.y * rzv.y;
    a0.z = pv0.z * rzv.z; a0.w = pv0.w * rzv.w;
    a1.x = pv1.x * rzv.x; a1.y = pv1.y * rzv.y;
    a1.z = pv1.z * rzv.z; a1.w = pv1.w * rzv.w;
    *(float4*)(attnB + (size_t)pr * TK + kc + pc) = a0;
    *(float4*)(attnB + (size_t)(pr + 32) * TK + kc + pc) = a1;
    *(ushort4*)&sh.b[B].a[pr][pc] =
        make_ushort4(f2bf(a0.x), f2bf(a0.y), f2bf(a0.z), f2bf(a0.w));
    *(ushort4*)&sh.b[B].a[pr + 32][pc] =
        make_ushort4(f2bf(a1.x), f2bf(a1.y), f2bf(a1.z), f2bf(a1.w));
    *(uint4*)&sh.b[B].vh[vr][vc] = vh0;
    *(uint4*)&sh.b[B].vh[vr + 64][vc] = vh1;
    *(uint4*)&sh.b[B].vl[vr][vc] = vl0;
    *(uint4*)&sh.b[B].vl[vr + 64][vc] = vl1;
  };

  load_chunk(0);
  stage_chunk(0, 0);
  __syncthreads();

  int cur = 0;
  constexpr int NT = TK / 32;
  for (int t = 0; t < NT; ++t) {
    if (t + 1 < NT) load_chunk((t + 1) * 32);

    s8v vhf[4], vlf[4], pf[2];
#pragma unroll
    for (int i = 0; i < 4; ++i) {
      vhf[i] = *(const s8v*)&sh.b[cur].vh[wr * 64 + i * 16 + l16][quad * 8];
      vlf[i] = *(const s8v*)&sh.b[cur].vl[wr * 64 + i * 16 + l16][quad * 8];
    }
#pragma unroll
    for (int j = 0; j < 2; ++j)
      pf[j] = *(const s8v*)&sh.b[cur].a[wc * 32 + j * 16 + l16][quad * 8];

#pragma unroll
    for (int i = 0; i < 4; ++i)
#pragma unroll
      for (int j = 0; j < 2; ++j) {
        acc[i][j] = __builtin_amdgcn_mfma_f32_16x16x32_bf16(vhf[i], pf[j], acc[i][j], 0, 0, 0);
        acc[i][j] = __builtin_amdgcn_mfma_f32_16x16x32_bf16(vlf[i], pf[j], acc[i][j], 0, 0, 0);
      }

    if (t + 1 < NT) {
      stage_chunk((t + 1) * 32, cur ^ 1);
      __syncthreads();
      cur ^= 1;
    }
  }

  __syncthreads();
#pragma unroll
  for (int i = 0; i < 4; ++i)
#pragma unroll
    for (int j = 0; j < 2; ++j)
#pragma unroll
      for (int r = 0; r < 4; ++r)
        sh.ctx[wc * 32 + j * 16 + l16][wr * 64 + i * 16 + quad * 4 + r] = acc[i][j][r];
  __syncthreads();
#pragma unroll
  for (int it = 0; it < 8; ++it) {
    int idx = it * 256 + tid;
    int r = idx >> 5, c = (idx & 31) * 4;
    float4 v;
    v.x = sh.ctx[r][c];     v.y = sh.ctx[r][c + 1];
    v.z = sh.ctx[r][c + 2]; v.w = sh.ctx[r][c + 3];
    *(float4*)(Ctx + ((size_t)b * TQ + qb * 64 + r) * DH + c) = v;
  }
}

// ---------------------------------------------------------------------------
extern "C" void kernel_launch(void* const* d_in, const int* in_sizes, int n_in,
                              void* d_out, int out_size, void* d_ws, size_t ws_size,
                              hipStream_t stream)
{
  const float* Q = (const float*)d_in[0];
  const float* K = (const float*)d_in[1];
  const float* V = (const float*)d_in[2];
  const float* M = (const float*)d_in[3];

  float* ctx  = (float*)d_out;
  float* attn = ctx + (size_t)BN * TQ * DH;   // outputs: context ++ attn

  // workspace layout:
  //   Z  @ 0       (128 KB)
  //   Rz @ 128KB   (128 KB)
  //   Vthi @ 1MB   (8 MB)
  //   Vtlo @ 9MB   (8 MB)
  char* ws = (char*)d_ws;
  float* Z  = (float*)ws;
  float* Rz = (float*)(ws + (128 << 10));
  unsigned short* Vthi = (unsigned short*)(ws + (1 << 20));
  unsigned short* Vtlo = Vthi + (size_t)BN * DH * TK;

  hipMemsetAsync(Z, 0, (size_t)BN * TK * sizeof(float), stream);
  vtrans_kernel<<<dim3(TK/64, DH/64, BN), 256, 0, stream>>>(V, Vthi, Vtlo);
  qk_exp_kernel<<<dim3(TK/128, TQ/128, BN), 256, 0, stream>>>(Q, K, M, attn, Z);
  rz_kernel<<<dim3((BN*TK)/256), 256, 0, stream>>>(Z, Rz);
  av_kernel<<<dim3(TQ/64, BN), 256, 0, stream>>>(attn, Vthi, Vtlo, Rz, ctx);
}

// Round 5
// 660.868 us; speedup vs baseline: 1.3679x; 1.0747x over previous
//
#include <hip/hip_runtime.h>

typedef __attribute__((ext_vector_type(8))) short s8v;
typedef __attribute__((ext_vector_type(4))) float f4v;

constexpr int BN = 16;
constexpr int TQ = 2048;
constexpr int TK = 2048;
constexpr int DH = 128;

__device__ __forceinline__ unsigned short f2bf(float f) {
  unsigned int u = __float_as_uint(f);
  u += 0x7fffu + ((u >> 16) & 1u);   // round-to-nearest-even
  return (unsigned short)(u >> 16);
}
__device__ __forceinline__ float bf2f(unsigned short h) {
  return __uint_as_float(((unsigned int)h) << 16);
}

// ---------------------------------------------------------------------------
// Kernel 1: S = Q K^T / sqrt(D); P = (masked ? 0 : exp(S));
//           Z[b,k] += column sums (softmax is over the q axis!).
// template PB16: 1 -> store P as bf16 into workspace Pb (halves write traffic;
//                     downstream MFMA uses bf16 anyway)
//                0 -> legacy f32 store into attn region
// ---------------------------------------------------------------------------
union QKSH {
  struct {
    unsigned short qhi[128][40];
    unsigned short qlo[128][40];
    unsigned short khi[128][40];
    unsigned short klo[128][40];
  } s;                                  // 40960 B (MFMA phase)
  unsigned short msk[128][132];         // 33792 B (epilogue phase)
};

template<int PB16>
__global__ __launch_bounds__(256, 4) void qk_exp_kernel(
    const float* __restrict__ Q, const float* __restrict__ K,
    const float* __restrict__ Msk, float* __restrict__ P,
    unsigned short* __restrict__ Pb, float* __restrict__ Z)
{
  __shared__ QKSH sh;

  const int kb = blockIdx.x, qb = blockIdx.y, b = blockIdx.z;
  const int tid = threadIdx.x;
  const int wave = tid >> 6, lane = tid & 63;
  const int wr = wave >> 1, wc = wave & 1;
  const int quad = lane >> 4, l16 = lane & 15;

  f4v acc[4][4];
#pragma unroll
  for (int i = 0; i < 4; ++i)
#pragma unroll
    for (int j = 0; j < 4; ++j)
      acc[i][j] = (f4v){0.f, 0.f, 0.f, 0.f};

  const float* Qb = Q + ((size_t)b * TQ + (size_t)qb * 128) * DH;
  const float* Kb = K + ((size_t)b * TK + (size_t)kb * 128) * DH;

  for (int dc = 0; dc < DH; dc += 32) {
    __syncthreads();
#pragma unroll
    for (int i = 0; i < 4; ++i) {
      int idx = i * 256 + tid;
      int r = idx >> 3, c = (idx & 7) * 4;
      float4 qv = *(const float4*)(Qb + (size_t)r * DH + dc + c);
      float4 kv = *(const float4*)(Kb + (size_t)r * DH + dc + c);
      unsigned short h;
      h = f2bf(qv.x); sh.s.qhi[r][c+0] = h; sh.s.qlo[r][c+0] = f2bf(qv.x - bf2f(h));
      h = f2bf(qv.y); sh.s.qhi[r][c+1] = h; sh.s.qlo[r][c+1] = f2bf(qv.y - bf2f(h));
      h = f2bf(qv.z); sh.s.qhi[r][c+2] = h; sh.s.qlo[r][c+2] = f2bf(qv.z - bf2f(h));
      h = f2bf(qv.w); sh.s.qhi[r][c+3] = h; sh.s.qlo[r][c+3] = f2bf(qv.w - bf2f(h));
      h = f2bf(kv.x); sh.s.khi[r][c+0] = h; sh.s.klo[r][c+0] = f2bf(kv.x - bf2f(h));
      h = f2bf(kv.y); sh.s.khi[r][c+1] = h; sh.s.klo[r][c+1] = f2bf(kv.y - bf2f(h));
      h = f2bf(kv.z); sh.s.khi[r][c+2] = h; sh.s.klo[r][c+2] = f2bf(kv.z - bf2f(h));
      h = f2bf(kv.w); sh.s.khi[r][c+3] = h; sh.s.klo[r][c+3] = f2bf(kv.w - bf2f(h));
    }
    __syncthreads();

    s8v ah[4], al[4];
#pragma unroll
    for (int i = 0; i < 4; ++i) {
      ah[i] = *(const s8v*)&sh.s.qhi[wr*64 + i*16 + l16][quad*8];
      al[i] = *(const s8v*)&sh.s.qlo[wr*64 + i*16 + l16][quad*8];
    }
#pragma unroll
    for (int j = 0; j < 4; ++j) {
      s8v bh = *(const s8v*)&sh.s.khi[wc*64 + j*16 + l16][quad*8];
      s8v bl = *(const s8v*)&sh.s.klo[wc*64 + j*16 + l16][quad*8];
#pragma unroll
      for (int i = 0; i < 4; ++i) {
        acc[i][j] = __builtin_amdgcn_mfma_f32_16x16x32_bf16(ah[i], bh, acc[i][j], 0, 0, 0);
        acc[i][j] = __builtin_amdgcn_mfma_f32_16x16x32_bf16(al[i], bh, acc[i][j], 0, 0, 0);
        acc[i][j] = __builtin_amdgcn_mfma_f32_16x16x32_bf16(ah[i], bl, acc[i][j], 0, 0, 0);
      }
    }
  }

  // ---- mask restage into dead Q/K LDS
  __syncthreads();
  {
    const float* MB = Msk + ((size_t)b * TQ + (size_t)qb * 128) * TK + (size_t)kb * 128;
#pragma unroll
    for (int it = 0; it < 16; ++it) {
      int idx = it * 256 + tid;
      int r = idx >> 5, c = (idx & 31) * 4;
      float4 mv = *(const float4*)(MB + (size_t)r * TK + c);
      ushort4 mu;
      mu.x = (mv.x != 0.f); mu.y = (mv.y != 0.f);
      mu.z = (mv.z != 0.f); mu.w = (mv.w != 0.f);
      *(ushort4*)&sh.msk[r][c] = mu;
    }
  }
  __syncthreads();

  const float scale = 0.08838834764831845f;  // 1/sqrt(128)
  float csum[4] = {0.f, 0.f, 0.f, 0.f};
#pragma unroll
  for (int i = 0; i < 4; ++i) {
    int lr0 = wr * 64 + i * 16 + quad * 4;     // local row within tile
#pragma unroll
    for (int r = 0; r < 4; ++r) {
      size_t rowoff = ((size_t)b * TQ + qb * 128 + lr0 + r) * TK + kb * 128 + wc * 64;
      const unsigned short* mrow = &sh.msk[lr0 + r][wc * 64];
#pragma unroll
      for (int j = 0; j < 4; ++j) {
        unsigned short m = mrow[j * 16 + l16];
        float p = m ? 0.f : __expf(acc[i][j][r] * scale);
        if constexpr (PB16)
          Pb[rowoff + j * 16 + l16] = f2bf(p);   // f2bf(0)==0 exactly
        else
          P[rowoff + j * 16 + l16] = p;
        csum[j] += p;
      }
    }
  }
#pragma unroll
  for (int j = 0; j < 4; ++j) {
    float v = csum[j];
    v += __shfl_xor(v, 16, 64);
    v += __shfl_xor(v, 32, 64);
    if (quad == 0)
      atomicAdd(&Z[b * TK + kb * 128 + wc * 64 + j * 16 + l16], v);
  }
}

// ---------------------------------------------------------------------------
// Kernel 2a: V[b,k,d] -> Vt_hi/Vt_lo[b,d,k] (bf16 split planes) via LDS tile.
// template SCALE: fold rz[k] into the planes (runs after rz_kernel) so av's
// MFMA consumes pre-normalized V and its staging is a pure copy.
// ---------------------------------------------------------------------------
template<bool SCALE>
__global__ __launch_bounds__(256) void vtrans_kernel(
    const float* __restrict__ V, const float* __restrict__ Rz,
    unsigned short* __restrict__ Vthi, unsigned short* __restrict__ Vtlo)
{
  __shared__ float tile[64][65];
  const int k0 = blockIdx.x * 64, d0 = blockIdx.y * 64, b = blockIdx.z;
  const int tid = threadIdx.x;
#pragma unroll
  for (int i = 0; i < 4; ++i) {
    int idx = i * 256 + tid;
    int r = idx >> 4, c = (idx & 15) * 4;
    float4 v = *(const float4*)(V + ((size_t)b * TK + k0 + r) * DH + d0 + c);
    tile[r][c] = v.x; tile[r][c+1] = v.y; tile[r][c+2] = v.z; tile[r][c+3] = v.w;
  }
  __syncthreads();
  const int dr = tid >> 2, kq = (tid & 3) * 16;
  float rzbuf[16];
  if constexpr (SCALE) {
#pragma unroll
    for (int m = 0; m < 4; ++m) {
      float4 rv = *(const float4*)(Rz + (size_t)b * TK + k0 + kq + 4 * m);
      rzbuf[4*m] = rv.x; rzbuf[4*m+1] = rv.y; rzbuf[4*m+2] = rv.z; rzbuf[4*m+3] = rv.w;
    }
  }
  size_t base = ((size_t)b * DH + d0 + dr) * TK + k0 + kq;
  unsigned short hbuf[16], lbuf[16];
#pragma unroll
  for (int j = 0; j < 16; ++j) {
    float f = tile[kq + j][dr];
    if constexpr (SCALE) f *= rzbuf[j];
    unsigned short h = f2bf(f);
    hbuf[j] = h;
    lbuf[j] = f2bf(f - bf2f(h));
  }
#pragma unroll
  for (int m = 0; m < 4; ++m) {
    ushort4 hv = make_ushort4(hbuf[4*m], hbuf[4*m+1], hbuf[4*m+2], hbuf[4*m+3]);
    ushort4 lv = make_ushort4(lbuf[4*m], lbuf[4*m+1], lbuf[4*m+2], lbuf[4*m+3]);
    *(ushort4*)(Vthi + base + 4*m) = hv;
    *(ushort4*)(Vtlo + base + 4*m) = lv;
  }
}

// Kernel 2b: Rz = 1/Z
__global__ __launch_bounds__(256) void rz_kernel(const float* __restrict__ Z,
                                                 float* __restrict__ Rz) {
  int i = blockIdx.x * 256 + threadIdx.x;
  Rz[i] = 1.0f / Z[i];
}

// ---------------------------------------------------------------------------
// Kernel 3 (big-ws path): reads Pb bf16, writes attn f32 = bf2f(pb)*rz,
// context = Pb @ (V*rz) with pre-scaled split planes. Staging is pure copies.
// ---------------------------------------------------------------------------
union __align__(16) AVSH {
  struct {
    unsigned short a[64][40];    // attn tile, bf16
    unsigned short vh[128][40];  // V^T hi plane
    unsigned short vl[128][40];  // V^T lo plane
  } b[2];                        // double buffer: 2 x 25600 B = 50 KB
  float ctx[64][131];            // epilogue transpose
};

__global__ __launch_bounds__(256) void av_kernel_b(
    const unsigned short* __restrict__ Pb, float* __restrict__ Attn,
    const unsigned short* __restrict__ Vthi, const unsigned short* __restrict__ Vtlo,
    const float* __restrict__ Rz, float* __restrict__ Ctx)
{
  __shared__ AVSH sh;
  const int qb = blockIdx.x, b = blockIdx.y;
  const int tid = threadIdx.x;
  const int wave = tid >> 6, lane = tid & 63;
  const int wr = wave >> 1, wc = wave & 1;
  const int quad = lane >> 4, l16 = lane & 15;

  f4v acc[4][2];
#pragma unroll
  for (int i = 0; i < 4; ++i)
#pragma unroll
    for (int j = 0; j < 2; ++j)
      acc[i][j] = (f4v){0.f, 0.f, 0.f, 0.f};

  const unsigned short* pbB = Pb + ((size_t)b * TQ + (size_t)qb * 64) * TK;
  float* attnB = Attn + ((size_t)b * TQ + (size_t)qb * 64) * TK;
  const unsigned short* vhB = Vthi + (size_t)b * DH * TK;
  const unsigned short* vlB = Vtlo + (size_t)b * DH * TK;
  const float* rzB = Rz + (size_t)b * TK;

  const int ar = tid >> 2, ac = (tid & 3) * 8;   // a-tile: 64 rows x 32 cols
  const int vr = tid >> 2, vc = (tid & 3) * 8;   // V planes: 128 rows x 32 cols

  s8v pa;
  float4 rz0, rz1;
  uint4 vh0, vh1, vl0, vl1;

  auto load_chunk = [&](int kc) {
    pa  = *(const s8v*)(pbB + (size_t)ar * TK + kc + ac);
    rz0 = *(const float4*)(rzB + kc + ac);
    rz1 = *(const float4*)(rzB + kc + ac + 4);
    vh0 = *(const uint4*)(vhB + (size_t)vr * TK + kc + vc);
    vh1 = *(const uint4*)(vhB + (size_t)(vr + 64) * TK + kc + vc);
    vl0 = *(const uint4*)(vlB + (size_t)vr * TK + kc + vc);
    vl1 = *(const uint4*)(vlB + (size_t)(vr + 64) * TK + kc + vc);
  };

  auto stage_chunk = [&](int kc, int B) {
    float4 w0, w1;
    w0.x = bf2f((unsigned short)pa[0]) * rz0.x;
    w0.y = bf2f((unsigned short)pa[1]) * rz0.y;
    w0.z = bf2f((unsigned short)pa[2]) * rz0.z;
    w0.w = bf2f((unsigned short)pa[3]) * rz0.w;
    w1.x = bf2f((unsigned short)pa[4]) * rz1.x;
    w1.y = bf2f((unsigned short)pa[5]) * rz1.y;
    w1.z = bf2f((unsigned short)pa[6]) * rz1.z;
    w1.w = bf2f((unsigned short)pa[7]) * rz1.w;
    *(float4*)(attnB + (size_t)ar * TK + kc + ac) = w0;        // final attn
    *(float4*)(attnB + (size_t)ar * TK + kc + ac + 4) = w1;
    *(s8v*)&sh.b[B].a[ar][ac] = pa;
    *(uint4*)&sh.b[B].vh[vr][vc] = vh0;
    *(uint4*)&sh.b[B].vh[vr + 64][vc] = vh1;
    *(uint4*)&sh.b[B].vl[vr][vc] = vl0;
    *(uint4*)&sh.b[B].vl[vr + 64][vc] = vl1;
  };

  load_chunk(0);
  stage_chunk(0, 0);
  __syncthreads();

  int cur = 0;
  constexpr int NT = TK / 32;
  for (int t = 0; t < NT; ++t) {
    if (t + 1 < NT) load_chunk((t + 1) * 32);

    s8v vhf[4], vlf[4], pf[2];
#pragma unroll
    for (int i = 0; i < 4; ++i) {
      vhf[i] = *(const s8v*)&sh.b[cur].vh[wr * 64 + i * 16 + l16][quad * 8];
      vlf[i] = *(const s8v*)&sh.b[cur].vl[wr * 64 + i * 16 + l16][quad * 8];
    }
#pragma unroll
    for (int j = 0; j < 2; ++j)
      pf[j] = *(const s8v*)&sh.b[cur].a[wc * 32 + j * 16 + l16][quad * 8];

#pragma unroll
    for (int i = 0; i < 4; ++i)
#pragma unroll
      for (int j = 0; j < 2; ++j) {
        acc[i][j] = __builtin_amdgcn_mfma_f32_16x16x32_bf16(vhf[i], pf[j], acc[i][j], 0, 0, 0);
        acc[i][j] = __builtin_amdgcn_mfma_f32_16x16x32_bf16(vlf[i], pf[j], acc[i][j], 0, 0, 0);
      }

    if (t + 1 < NT) {
      stage_chunk((t + 1) * 32, cur ^ 1);
      __syncthreads();
      cur ^= 1;
    }
  }

  __syncthreads();
#pragma unroll
  for (int i = 0; i < 4; ++i)
#pragma unroll
    for (int j = 0; j < 2; ++j)
#pragma unroll
      for (int r = 0; r < 4; ++r)
        sh.ctx[wc * 32 + j * 16 + l16][wr * 64 + i * 16 + quad * 4 + r] = acc[i][j][r];
  __syncthreads();
#pragma unroll
  for (int it = 0; it < 8; ++it) {
    int idx = it * 256 + tid;
    int r = idx >> 5, c = (idx & 31) * 4;
    float4 v;
    v.x = sh.ctx[r][c];     v.y = sh.ctx[r][c + 1];
    v.z = sh.ctx[r][c + 2]; v.w = sh.ctx[r][c + 3];
    *(float4*)(Ctx + ((size_t)b * TQ + qb * 64 + r) * DH + c) = v;
  }
}

// ---------------------------------------------------------------------------
// Kernel 3 (fallback path, small ws): round-3 av verbatim (f32 P in-place).
// ---------------------------------------------------------------------------
__global__ __launch_bounds__(256) void av_kernel_f(
    float* __restrict__ Attn, const unsigned short* __restrict__ Vthi,
    const unsigned short* __restrict__ Vtlo, const float* __restrict__ Rz,
    float* __restrict__ Ctx)
{
  __shared__ AVSH sh;
  const int qb = blockIdx.x, b = blockIdx.y;
  const int tid = threadIdx.x;
  const int wave = tid >> 6, lane = tid & 63;
  const int wr = wave >> 1, wc = wave & 1;
  const int quad = lane >> 4, l16 = lane & 15;

  f4v acc[4][2];
#pragma unroll
  for (int i = 0; i < 4; ++i)
#pragma unroll
    for (int j = 0; j < 2; ++j)
      acc[i][j] = (f4v){0.f, 0.f, 0.f, 0.f};

  float* attnB = Attn + ((size_t)b * TQ + (size_t)qb * 64) * TK;
  const unsigned short* vhB = Vthi + (size_t)b * DH * TK;
  const unsigned short* vlB = Vtlo + (size_t)b * DH * TK;
  const float* rzB = Rz + (size_t)b * TK;

  const int pc = (tid & 7) * 4;
  const int pr = tid >> 3;
  const int vc = (tid & 3) * 8;
  const int vr = tid >> 2;

  float4 pv0, pv1, rzv;
  uint4 vh0, vh1, vl0, vl1;

  auto load_chunk = [&](int kc) {
    pv0 = *(const float4*)(attnB + (size_t)pr * TK + kc + pc);
    pv1 = *(const float4*)(attnB + (size_t)(pr + 32) * TK + kc + pc);
    rzv = *(const float4*)(rzB + kc + pc);
    vh0 = *(const uint4*)(vhB + (size_t)vr * TK + kc + vc);
    vh1 = *(const uint4*)(vhB + (size_t)(vr + 64) * TK + kc + vc);
    vl0 = *(const uint4*)(vlB + (size_t)vr * TK + kc + vc);
    vl1 = *(const uint4*)(vlB + (size_t)(vr + 64) * TK + kc + vc);
  };

  auto stage_chunk = [&](int kc, int B) {
    float4 a0, a1;
    a0.x = pv0.x * rzv.x; a0.y = pv0.y * rzv.y;
    a0.z = pv0.z * rzv.z; a0.w = pv0.w * rzv.w;
    a1.x = pv1.x * rzv.x; a1.y = pv1.y * rzv.y;
    a1.z = pv1.z * rzv.z; a1.w = pv1.w * rzv.w;
    *(float4*)(attnB + (size_t)pr * TK + kc + pc) = a0;
    *(float4*)(attnB + (size_t)(pr + 32) * TK + kc + pc) = a1;
    *(ushort4*)&sh.b[B].a[pr][pc] =
        make_ushort4(f2bf(a0.x), f2bf(a0.y), f2bf(a0.z), f2bf(a0.w));
    *(ushort4*)&sh.b[B].a[pr + 32][pc] =
        make_ushort4(f2bf(a1.x), f2bf(a1.y), f2bf(a1.z), f2bf(a1.w));
    *(uint4*)&sh.b[B].vh[vr][vc] = vh0;
    *(uint4*)&sh.b[B].vh[vr + 64][vc] = vh1;
    *(uint4*)&sh.b[B].vl[vr][vc] = vl0;
    *(uint4*)&sh.b[B].vl[vr + 64][vc] = vl1;
  };

  load_chunk(0);
  stage_chunk(0, 0);
  __syncthreads();

  int cur = 0;
  constexpr int NT = TK / 32;
  for (int t = 0; t < NT; ++t) {
    if (t + 1 < NT) load_chunk((t + 1) * 32);

    s8v vhf[4], vlf[4], pf[2];
#pragma unroll
    for (int i = 0; i < 4; ++i) {
      vhf[i] = *(const s8v*)&sh.b[cur].vh[wr * 64 + i * 16 + l16][quad * 8];
      vlf[i] = *(const s8v*)&sh.b[cur].vl[wr * 64 + i * 16 + l16][quad * 8];
    }
#pragma unroll
    for (int j = 0; j < 2; ++j)
      pf[j] = *(const s8v*)&sh.b[cur].a[wc * 32 + j * 16 + l16][quad * 8];

#pragma unroll
    for (int i = 0; i < 4; ++i)
#pragma unroll
      for (int j = 0; j < 2; ++j) {
        acc[i][j] = __builtin_amdgcn_mfma_f32_16x16x32_bf16(vhf[i], pf[j], acc[i][j], 0, 0, 0);
        acc[i][j] = __builtin_amdgcn_mfma_f32_16x16x32_bf16(vlf[i], pf[j], acc[i][j], 0, 0, 0);
      }

    if (t + 1 < NT) {
      stage_chunk((t + 1) * 32, cur ^ 1);
      __syncthreads();
      cur ^= 1;
    }
  }

  __syncthreads();
#pragma unroll
  for (int i = 0; i < 4; ++i)
#pragma unroll
    for (int j = 0; j < 2; ++j)
#pragma unroll
      for (int r = 0; r < 4; ++r)
        sh.ctx[wc * 32 + j * 16 + l16][wr * 64 + i * 16 + quad * 4 + r] = acc[i][j][r];
  __syncthreads();
#pragma unroll
  for (int it = 0; it < 8; ++it) {
    int idx = it * 256 + tid;
    int r = idx >> 5, c = (idx & 31) * 4;
    float4 v;
    v.x = sh.ctx[r][c];     v.y = sh.ctx[r][c + 1];
    v.z = sh.ctx[r][c + 2]; v.w = sh.ctx[r][c + 3];
    *(float4*)(Ctx + ((size_t)b * TQ + qb * 64 + r) * DH + c) = v;
  }
}

// ---------------------------------------------------------------------------
extern "C" void kernel_launch(void* const* d_in, const int* in_sizes, int n_in,
                              void* d_out, int out_size, void* d_ws, size_t ws_size,
                              hipStream_t stream)
{
  const float* Q = (const float*)d_in[0];
  const float* K = (const float*)d_in[1];
  const float* V = (const float*)d_in[2];
  const float* M = (const float*)d_in[3];

  float* ctx  = (float*)d_out;
  float* attn = ctx + (size_t)BN * TQ * DH;   // outputs: context ++ attn

  char* ws = (char*)d_ws;
  const size_t pbBytes = (size_t)BN * TQ * TK * 2;        // 134 MB
  const size_t bigNeed = (19ull << 20) + pbBytes;         // ~153.2 MB

  if (ws_size >= bigNeed) {
    // big-ws path: Z@0 | Rz@512K | Vthi@1M | Vtlo@10M | Pb@19M
    float* Z  = (float*)ws;
    float* Rz = (float*)(ws + (512 << 10));
    unsigned short* Vthi = (unsigned short*)(ws + (1u << 20));
    unsigned short* Vtlo = (unsigned short*)(ws + (10u << 20));
    unsigned short* Pb   = (unsigned short*)(ws + (19u << 20));

    hipMemsetAsync(Z, 0, (size_t)BN * TK * sizeof(float), stream);
    qk_exp_kernel<1><<<dim3(TK/128, TQ/128, BN), 256, 0, stream>>>(Q, K, M, nullptr, Pb, Z);
    rz_kernel<<<dim3((BN*TK)/256), 256, 0, stream>>>(Z, Rz);
    vtrans_kernel<true><<<dim3(TK/64, DH/64, BN), 256, 0, stream>>>(V, Rz, Vthi, Vtlo);
    av_kernel_b<<<dim3(TQ/64, BN), 256, 0, stream>>>(Pb, attn, Vthi, Vtlo, Rz, ctx);
  } else {
    // fallback: round-3 pipeline verbatim
    float* Z  = (float*)ws;
    float* Rz = (float*)(ws + (128 << 10));
    unsigned short* Vthi = (unsigned short*)(ws + (1u << 20));
    unsigned short* Vtlo = Vthi + (size_t)BN * DH * TK;

    hipMemsetAsync(Z, 0, (size_t)BN * TK * sizeof(float), stream);
    vtrans_kernel<false><<<dim3(TK/64, DH/64, BN), 256, 0, stream>>>(V, nullptr, Vthi, Vtlo);
    qk_exp_kernel<0><<<dim3(TK/128, TQ/128, BN), 256, 0, stream>>>(Q, K, M, attn, nullptr, Z);
    rz_kernel<<<dim3((BN*TK)/256), 256, 0, stream>>>(Z, Rz);
    av_kernel_f<<<dim3(TQ/64, BN), 256, 0, stream>>>(attn, Vthi, Vtlo, Rz, ctx);
  }
}